// Round 5
// baseline (695.204 us; speedup 1.0000x reference)
//
#include <hip/hip_runtime.h>

// gConv3d separable factorization:
//   q[n,o,b,h,w]   = sum_{c,f} x[c, n+f, h, w] * weight[o,c,f,b]        (K=216)
//   s[n,g,o,ii,jj] = sum_{b,u,v} q[n,o,b,ii+u,jj+v] * basis[g][(b,u,v)] (K=63)
//   out[g*8+o, xo+1,yo+1,zo+1, h, w] = s[n, T(g,h,w), o, clip(h)-1, clip(w)-1] + bias_sum[o]
// T(g,h,w) = (g+1)%12 on the (h,w) border, else g. Non-interior xyz = 0.
//
// R9 = R8 resubmitted verbatim (R8 bench was an infra failure: "container
// failed twice", no compile/test/counter output; kernel audited for OOB /
// hang / capture violations — none found).
//
// R8 redesign rationale. Evidence from R4-R7: VALU busy-time invariant
// ~77-83 us, duty pinned at 46% regardless of operand placement (LDS->SGPR
// null, weight-reuse x3 null). Root causes are structural:
//  (a) OG<=2 gives only 63-126 FMA-cyc per x-load group vs ~300 cyc L2
//      latency, and the 8 o-blocks of one n RE-READ the same x taps
//      (2.7 GB L2 traffic, 57 KB L1 set -> L1 useless, correlated vmcnt
//      convoys across in-phase waves);
//  (b) 7.6 blocks/CU with 6 resident -> ~2 serial rounds (tail quantization).
// Fix: block = (n, ALL 8 o). acc[8][7]=56 VGPRs.
//  - each x tap feeds 56 FMAs; per (fi,fj): 3 loads -> 336 FMA-cyc >=
//    latency -> single-wave self-hiding; x L2 traffic /8.
//  - grid = 729 blocks, <=3 needed/CU, 4 fit (LDS 35840, VGPR cap 128)
//    -> ALL blocks co-resident, single round, no tail.
//  - stage 2 in two 4-o phases through qs (35840 B); phase loop fully
//    unrolled so all acc[] indices are compile-time (no scratch).
//  - launch_bounds(320,4): 128-VGPR cap, big margin vs R6's spill mode.
// Sentinels: WRITE_SIZE must stay exactly 207360 KB (else spill).
// Floors: FMA 54 us, VALU ~75 us total. Target 80-105 us.

#define HW 320
#define NB 729    // one block per n, all 8 o inside

__global__ __launch_bounds__(320, 4) void fused_kernel(
    const float* __restrict__ x, const float* __restrict__ weight,
    const float* __restrict__ bias, const float* __restrict__ basis,
    float* __restrict__ out)
{
    __shared__ float qs[4 * 7 * HW];   // 35840 B, 4-o phase buffer

    const int tid = threadIdx.x;

    // ---- border zero-fill (grid-strided, masked, coalesced; stores are
    // fire-and-forget and drain under stage-1 compute) ----
    {
        float4* out4 = (float4*)out;
        const float4 z = make_float4(0.f, 0.f, 0.f, 0.f);
        #pragma unroll 1
        for (int s = blockIdx.x * 320 + tid; s < 96 * 1728 * 80; s += NB * 320) {
            int row = s / 80;                      // go*1728 + xyz
            int xyz = row - (row / 1728) * 1728;
            int xi = xyz / 144;
            int r2 = xyz - xi * 144;
            int yi = r2 / 12;
            int zi = r2 - yi * 12;
            if (!((unsigned)(xi - 1) < 9u && (unsigned)(yi - 1) < 9u &&
                  (unsigned)(zi - 1) < 9u))
                out4[s] = z;
        }
    }

    const int n  = blockIdx.x;                    // 0..728
    const int xo = n / 81;
    const int rem = n - xo * 81;
    const int yo = rem / 9;
    const int zo = rem - yo * 9;

    // ---------------- stage 1: q for all 8 o into registers ----------------
    float acc[56];                                // [o][b], all indices static
    #pragma unroll
    for (int i = 0; i < 56; ++i) acc[i] = 0.f;

    const float* xb = x + ((xo * 12 + yo) * 12 + zo) * HW + tid;

    #pragma unroll 1
    for (int c = 0; c < 8; ++c) {
        const float* xc  = xb + c * 1728 * HW;
        const float* wcb = weight + c * 189;      // uniform -> s_load
        #pragma unroll
        for (int fi = 0; fi < 3; ++fi) {
            #pragma unroll
            for (int fj = 0; fj < 3; ++fj) {
                float xv[3];
                #pragma unroll
                for (int fk = 0; fk < 3; ++fk)
                    xv[fk] = xc[(fi * 144 + fj * 12 + fk) * HW];
                // each xv feeds 56 FMAs (8 o x 7 b)
                #pragma unroll
                for (int o = 0; o < 8; ++o) {
                    const float* wp = wcb + o * 1512 + fi * 63 + fj * 21; // 21 contiguous floats
                    #pragma unroll
                    for (int fk = 0; fk < 3; ++fk)
                        #pragma unroll
                        for (int b = 0; b < 7; ++b)
                            acc[o * 7 + b] = fmaf(xv[fk], wp[fk * 7 + b], acc[o * 7 + b]);
                }
            }
        }
    }

    // ---------------- stage 2: two 4-o phases through qs ----------------
    const int h = tid / 40;
    const int w = tid - h * 40;
    const int ii = min(max(h, 1), 6) - 1;    // 0..5
    const int jj = min(max(w, 1), 38) - 1;   // 0..37
    const bool border = (h == 0) | (h == 7) | (w == 0) | (w == 39);
    const int base_hw = ii * 40 + jj;
    const int out_xyz = ((xo + 1) * 144 + (yo + 1) * 12 + (zo + 1)) * HW + tid;

    #pragma unroll
    for (int p = 0; p < 2; ++p) {            // fully unrolled: acc idx static
        if (p) __syncthreads();              // protect qs reuse
        #pragma unroll
        for (int i = 0; i < 28; ++i)
            qs[i * HW + tid] = acc[p * 28 + i];
        __syncthreads();

        #pragma unroll 1
        for (int oo = 0; oo < 4; ++oo) {
            const int o = p * 4 + oo;
            float sv[12];
            #pragma unroll
            for (int g = 0; g < 12; ++g) sv[g] = 0.f;

            #pragma unroll 1
            for (int b = 0; b < 7; ++b) {
                float qw[9];
                #pragma unroll
                for (int uv = 0; uv < 9; ++uv) {
                    const int u = uv / 3, v = uv - (uv / 3) * 3;
                    qw[uv] = qs[(oo * 7 + b) * HW + base_hw + u * 40 + v];
                }
                const float* bb = basis + b * 9;
                #pragma unroll
                for (int g = 0; g < 12; ++g)
                    #pragma unroll
                    for (int uv = 0; uv < 9; ++uv)
                        sv[g] = fmaf(qw[uv], bb[g * 63 + uv], sv[g]);  // uniform s_load
            }

            float bs = 0.f;                  // wave-uniform bias sum
            #pragma unroll
            for (int i = 0; i < 27; ++i) bs += bias[o * 27 + i];

            #pragma unroll
            for (int g = 0; g < 12; ++g) {
                float val = (border ? sv[(g + 1) % 12] : sv[g]) + bs;
                out[(g * 8 + o) * (1728 * HW) + out_xyz] = val;
            }
        }
    }
}

extern "C" void kernel_launch(void* const* d_in, const int* in_sizes, int n_in,
                              void* d_out, int out_size, void* d_ws, size_t ws_size,
                              hipStream_t stream)
{
    const float* x      = (const float*)d_in[0];
    const float* weight = (const float*)d_in[1];
    const float* bias   = (const float*)d_in[2];
    const float* basis  = (const float*)d_in[3];
    float* out = (float*)d_out;

    fused_kernel<<<NB, 320, 0, stream>>>(x, weight, bias, basis, out);
}

// Round 6
// 350.567 us; speedup vs baseline: 1.9831x; 1.9831x over previous
//
#include <hip/hip_runtime.h>

// gConv3d separable factorization:
//   q[n,o,b,h,w]   = sum_{c,f} x[c, n+f, h, w] * weight[o,c,f,b]        (K=216)
//   s[n,g,o,ii,jj] = sum_{b,u,v} q[n,o,b,ii+u,jj+v] * basis[g][(b,u,v)] (K=63)
//   out[g*8+o, xo+1,yo+1,zo+1, h, w] = s[n, T(g,h,w), o, clip(h)-1, clip(w)-1] + bias_sum[o]
// T(g,h,w) = (g+1)%12 on the (h,w) border, else g. Non-interior xyz = 0.
//
// R10. Discovery from R4-R9 cross-analysis: per-wave VALU issue duty is a
// CONSTANT ~6.2% in every config (R7: 46.6%/7.5 waves; R9: 21.6%/3.56
// waves), so SIMD duty = 0.062 * waves/SIMD, capped ~50% at 8 waves. The
// pin: VGPR_Count=36 in all fast rounds -> compiler never batched x loads;
// stage-1 is serial load->waitcnt->use chains (MLP 1-5), ~10-15k stall cyc
// per c-iter vs ~1k issue. Reuse changes (R6/R7) were null because loads
// were never concurrently in flight. R9 additionally collapsed regalloc
// (VGPR 52 < acc 56 -> AGPR shuffling, VALU time 80->113 us).
// Fix (single change vs R5): batch ALL 27 taps of a c-iter into xv[27]
// before the FMA burst -> one load cluster, one vmcnt exposure, MLP 27.
//  - launch_bounds(320,8): VGPR cap 64. REQUIRED: >64 halves waves/SIMD
//    (m69). Estimated live set ~52-58. Spill sentinel: WRITE_SIZE must
//    stay exactly 207360 KB.
//  - everything else verbatim R5 (OG=2, 2928 blocks, qs 17920 B, stage-2
//    b-outer with s_load basis, XCD swizzle).
// Predict: VALUBusy 46->60-75%, dur 166 -> 100-130 us.

#define HW 320
#define OG 2          // o's per block (4 blocks per n)
#define NLOG 2916     // 729 n * 4 o-quarters
#define NPAD 2928     // 8 * 366

__global__ __launch_bounds__(320, 8) void fused_kernel(
    const float* __restrict__ x, const float* __restrict__ weight,
    const float* __restrict__ bias, const float* __restrict__ basis,
    float* __restrict__ out)
{
    __shared__ float qs[OG * 7 * HW];   // 17920 B

    const int tid = threadIdx.x;

    // ---- border zero-fill (grid-strided, masked, coalesced) ----
    {
        float4* out4 = (float4*)out;
        const float4 z = make_float4(0.f, 0.f, 0.f, 0.f);
        for (int s = blockIdx.x * 320 + tid; s < 96 * 1728 * 80; s += NPAD * 320) {
            int row = s / 80;                      // go*1728 + xyz
            int xyz = row - (row / 1728) * 1728;
            int xi = xyz / 144;
            int r2 = xyz - xi * 144;
            int yi = r2 / 12;
            int zi = r2 - yi * 12;
            if (!((unsigned)(xi - 1) < 9u && (unsigned)(yi - 1) < 9u &&
                  (unsigned)(zi - 1) < 9u))
                out4[s] = z;
        }
    }

    // XCD-aware swizzle: contiguous logical range per XCD; all 4 o-blocks of
    // one n stay on the same XCD (they share all 216 x taps).
    const int xcd  = blockIdx.x & 7;
    const int slot = blockIdx.x >> 3;
    const int logical = xcd * (NPAD / 8) + slot;
    if (logical >= NLOG) return;

    const int n  = logical >> 2;
    const int o0 = (logical & 3) * OG;
    const int xo = n / 81;
    const int rem = n - xo * 81;
    const int yo = rem / 9;
    const int zo = rem - yo * 9;

    // ---------------- stage 1: q into registers, batched tap loads ----------
    float acc[OG * 7];
    #pragma unroll
    for (int i = 0; i < OG * 7; ++i) acc[i] = 0.f;

    const float* xb = x + ((xo * 12 + yo) * 12 + zo) * HW + tid;

    #pragma unroll 1
    for (int c = 0; c < 8; ++c) {
        const float* xc = xb + c * 1728 * HW;

        // Batch ALL 27 tap loads first: 27 independent global_loads to
        // distinct VGPRs -> single issue cluster, MLP=27, ONE latency
        // exposure per c-iter (was ~27 serialized).
        float xv[27];
        #pragma unroll
        for (int t = 0; t < 27; ++t) {
            const int fi = t / 9, fj = (t / 3) % 3, fk = t % 3;
            xv[t] = xc[(fi * 144 + fj * 12 + fk) * HW];
        }

        const float* wc = weight + o0 * 1512 + c * 189;   // uniform -> s_load
        #pragma unroll
        for (int t = 0; t < 27; ++t) {
            const int fi = t / 9, fj = (t / 3) % 3, fk = t % 3;
            const float* wp = wc + fi * 63 + fj * 21 + fk * 7;
            #pragma unroll
            for (int oo = 0; oo < OG; ++oo)
                #pragma unroll
                for (int b = 0; b < 7; ++b)
                    acc[oo * 7 + b] = fmaf(xv[t], wp[oo * 1512 + b], acc[oo * 7 + b]);
        }
    }

    #pragma unroll
    for (int i = 0; i < OG * 7; ++i) qs[i * HW + tid] = acc[i];
    __syncthreads();

    // ---------------- stage 2: b-outer, basis via scalar loads ----------------
    const int h = tid / 40;
    const int w = tid - h * 40;
    const int ii = min(max(h, 1), 6) - 1;    // 0..5
    const int jj = min(max(w, 1), 38) - 1;   // 0..37
    const bool border = (h == 0) | (h == 7) | (w == 0) | (w == 39);
    const int base_hw = ii * 40 + jj;

    float s[OG][12];
    #pragma unroll
    for (int oo = 0; oo < OG; ++oo)
        #pragma unroll
        for (int g = 0; g < 12; ++g) s[oo][g] = 0.f;

    #pragma unroll 1
    for (int b = 0; b < 7; ++b) {
        // per-lane stencil values for this b -> registers (all indices static)
        float qw[OG][9];
        #pragma unroll
        for (int uv = 0; uv < 9; ++uv) {
            const int u = uv / 3, v = uv - (uv / 3) * 3;
            #pragma unroll
            for (int oo = 0; oo < OG; ++oo)
                qw[oo][uv] = qs[(oo * 7 + b) * HW + base_hw + u * 40 + v];
        }
        // basis[g][b][u][v]: wave-uniform address -> s_load, SGPR operand of v_fmac
        const float* bb = basis + b * 9;
        #pragma unroll
        for (int g = 0; g < 12; ++g) {
            #pragma unroll
            for (int uv = 0; uv < 9; ++uv) {
                const float bv = bb[g * 63 + uv];   // uniform -> s_load (K$-hit, 3 KB)
                #pragma unroll
                for (int oo = 0; oo < OG; ++oo)
                    s[oo][g] = fmaf(qw[oo][uv], bv, s[oo][g]);
            }
        }
    }

    // bias sums (wave-uniform s_loads, outside hot loop)
    float bs[OG];
    #pragma unroll
    for (int oo = 0; oo < OG; ++oo) {
        float t = 0.f;
        #pragma unroll
        for (int i = 0; i < 27; ++i) t += bias[(o0 + oo) * 27 + i];
        bs[oo] = t;
    }

    const int out_xyz = ((xo + 1) * 144 + (yo + 1) * 12 + (zo + 1)) * HW + tid;

    #pragma unroll
    for (int oo = 0; oo < OG; ++oo)
        #pragma unroll
        for (int g = 0; g < 12; ++g) {
            float val = (border ? s[oo][(g + 1) % 12] : s[oo][g]) + bs[oo];
            out[(g * 8 + o0 + oo) * (1728 * HW) + out_xyz] = val;
        }
}

extern "C" void kernel_launch(void* const* d_in, const int* in_sizes, int n_in,
                              void* d_out, int out_size, void* d_ws, size_t ws_size,
                              hipStream_t stream)
{
    const float* x      = (const float*)d_in[0];
    const float* weight = (const float*)d_in[1];
    const float* bias   = (const float*)d_in[2];
    const float* basis  = (const float*)d_in[3];
    float* out = (float*)d_out;

    fused_kernel<<<NPAD, 320, 0, stream>>>(x, weight, bias, basis, out);
}